// Round 5
// baseline (3148.282 us; speedup 1.0000x reference)
//
#include <hip/hip_runtime.h>

#define PROP_ALPHA 0.1f
#define PROP_KSTEPS 10

// ---------------- CSR build ----------------

__global__ void hist_kernel(const int* __restrict__ dst, int* __restrict__ degI, int E) {
    int e = blockIdx.x * blockDim.x + threadIdx.x;
    if (e < E) atomicAdd(&degI[dst[e]], 1);
}

__global__ void dinv_kernel(const int* __restrict__ degI, float* __restrict__ dinv, int N) {
    int i = blockIdx.x * blockDim.x + threadIdx.x;
    if (i < N) {
        float d = (float)(degI[i] + 1);   // + self loop
        dinv[i] = rsqrtf(d);
    }
}

// ---- 3-kernel device-wide exclusive scan (N <= 256*256) ----

__global__ __launch_bounds__(256) void scan1_kernel(const int* __restrict__ degI,
                                                    int* __restrict__ rowptr,
                                                    int* __restrict__ blockSums, int N) {
    __shared__ int s[256];
    int t = threadIdx.x;
    int idx = blockIdx.x * 256 + t;
    s[t] = (idx < N) ? degI[idx] : 0;
    __syncthreads();
    for (int off = 1; off < 256; off <<= 1) {
        int x = (t >= off) ? s[t - off] : 0;
        __syncthreads();
        s[t] += x;
        __syncthreads();
    }
    if (idx < N) rowptr[idx + 1] = s[t];           // block-local inclusive
    if (t == 255) blockSums[blockIdx.x] = s[255];
    if (blockIdx.x == 0 && t == 0) rowptr[0] = 0;
}

__global__ __launch_bounds__(256) void scan2_kernel(int* __restrict__ blockSums, int nB) {
    __shared__ int s[256];
    int t = threadIdx.x;
    s[t] = (t < nB) ? blockSums[t] : 0;
    __syncthreads();
    for (int off = 1; off < 256; off <<= 1) {
        int x = (t >= off) ? s[t - off] : 0;
        __syncthreads();
        s[t] += x;
        __syncthreads();
    }
    if (t < nB) blockSums[t] = (t == 0) ? 0 : s[t - 1];   // exclusive
}

__global__ void scan3_kernel(int* __restrict__ rowptr, const int* __restrict__ blockSums,
                             int N) {
    int idx = blockIdx.x * 256 + threadIdx.x;
    if (idx < N) rowptr[idx + 1] += blockSums[blockIdx.x];
}

__global__ void scatter_kernel(const int* __restrict__ src, const int* __restrict__ dst,
                               const int* __restrict__ rowptr, int* __restrict__ rowctr,
                               int* __restrict__ colidx, int E) {
    int e = blockIdx.x * blockDim.x + threadIdx.x;
    if (e < E) {
        int d = dst[e], s = src[e];
        int p = rowptr[d] + atomicAdd(&rowctr[d], 1);
        colidx[p] = s;
    }
}

// rechunk [N][64] -> [8][N][8]; grid = { ceil(N*8/256), 8 }
__global__ void rechunk_kernel(const float* __restrict__ in, float* __restrict__ out,
                               int N) {
    int c8 = blockIdx.y;
    int t2 = blockIdx.x * 256 + threadIdx.x;
    if (t2 < N * 8) {
        int i = t2 >> 3, c = t2 & 7;
        out[(size_t)c8 * N * 8 + t2] = in[(size_t)i * 64 + c8 * 8 + c];
    }
}

// ---------------- fused MLP (R3 version): h2 = relu(zx@W3 + v*b3^T)@W4 + b4 -------

__global__ __launch_bounds__(256) void fusedmlp_kernel(const float* __restrict__ zx,
                                                       const float* __restrict__ v,
                                                       const float* __restrict__ W3,
                                                       const float* __restrict__ b3,
                                                       const float* __restrict__ W4,
                                                       const float* __restrict__ b4,
                                                       float* __restrict__ h2, int N) {
    __shared__ float Ws[128 * 64];   // 32 KB, holds W3 then W4
    __shared__ float zs[32 * 65];    // padded rows
    __shared__ float ts[32 * 128];
    __shared__ float vs[32];
    int t = threadIdx.x;
    int r0 = blockIdx.x * 32;
    int rows = min(32, N - r0);
    for (int idx = t; idx < 64 * 128; idx += 256) Ws[idx] = W3[idx];
    for (int idx = t; idx < rows * 64; idx += 256) {
        int r = idx >> 6, k = idx & 63;
        zs[r * 65 + k] = zx[(size_t)r0 * 64 + idx];
    }
    if (t < rows) vs[t] = v[r0 + t];
    __syncthreads();
    // layer 1: ts = relu(zs @ W3 + vs*b3)
    {
        int col = t & 127, rg = t >> 7;
        float bc = b3[col];
        for (int r = rg; r < rows; r += 2) {
            float acc = vs[r] * bc;
            #pragma unroll
            for (int k = 0; k < 64; ++k) acc += zs[r * 65 + k] * Ws[k * 128 + col];
            ts[r * 128 + col] = fmaxf(acc, 0.0f);
        }
    }
    __syncthreads();
    for (int idx = t; idx < 128 * 64; idx += 256) Ws[idx] = W4[idx];
    __syncthreads();
    // layer 2: h2 = ts @ W4 + b4
    {
        int col = t & 63, rg = t >> 6;
        float bc = b4[col];
        for (int r = rg; r < rows; r += 4) {
            float acc = bc;
            #pragma unroll
            for (int k = 0; k < 128; ++k) acc += ts[r * 128 + k] * Ws[k * 64 + col];
            h2[(size_t)(r0 + r) * 64 + col] = acc;
        }
    }
}

// ---------------- propagation ----------------

// ones-vector propagation, wave per node, shuffle reduce
__global__ __launch_bounds__(256) void propvec_kernel(const float* __restrict__ vin,
                                                      const int* __restrict__ rowptr,
                                                      const int* __restrict__ colidx,
                                                      const float* __restrict__ dinv,
                                                      float* __restrict__ vout,
                                                      int N, int firstOnes) {
    int wave = threadIdx.x >> 6, lane = threadIdx.x & 63;
    int i = blockIdx.x * 4 + wave;
    if (i >= N) return;
    i = __builtin_amdgcn_readfirstlane(i);
    int beg = rowptr[i], end = rowptr[i + 1];
    float di = dinv[i];
    float acc = 0.0f;
    for (int e = beg + lane; e < end; e += 64) {
        int s = colidx[e];
        acc += dinv[s] * di * (firstOnes ? 1.0f : vin[s]);
    }
    #pragma unroll
    for (int off = 32; off >= 1; off >>= 1) acc += __shfl_xor(acc, off);
    if (lane == 0) {
        float self = firstOnes ? 1.0f : vin[i];
        vout[i] = (1.0f - PROP_ALPHA) * (acc + di * di * self) + PROP_ALPHA;
    }
}

// XCD-pinned channel-chunked propagation.
// 8 chunks x 8 channels, layout [8][N][8]; chunk = blockIdx & 7 so (by the
// blockIdx%8 round-robin XCD heuristic) each XCD's L2 only ever sees one
// 1.6 MB z_in chunk + 1.6 MB z_out chunk -> gathers hit L2.
// Wave = 1 node: 8 edge-groups x 8 channel-lanes; colidx/h stream via
// nontemporal loads so they don't evict z.
__global__ __launch_bounds__(256) void prop8_kernel(const float* __restrict__ zin,
                                                    long zpitch, int zstride,
                                                    const float* __restrict__ hch,
                                                    const int* __restrict__ rowptr,
                                                    const int* __restrict__ colidx,
                                                    const float* __restrict__ dinv,
                                                    float* __restrict__ zout,
                                                    long opitch, int ostride, int N) {
    int chunk = blockIdx.x & 7;
    int nb = blockIdx.x >> 3;
    int wave = threadIdx.x >> 6, lane = threadIdx.x & 63;
    int eg = lane >> 3, c = lane & 7;
    int i = nb * 4 + wave;
    if (i >= N) return;
    i = __builtin_amdgcn_readfirstlane(i);
    int beg = rowptr[i], end = rowptr[i + 1];
    float di = dinv[i];
    const float* zp = zin + (size_t)chunk * zpitch;
    float* op = zout + (size_t)chunk * opitch;
    const float* hp = hch + (size_t)chunk * N * 8;

    float acc0 = (eg == 0) ? di * di * zp[(size_t)i * zstride + c] : 0.0f;
    float acc1 = 0.0f;
    int e = beg + eg;
    for (; e + 8 < end; e += 16) {
        int s0 = __builtin_nontemporal_load(colidx + e);
        int s1 = __builtin_nontemporal_load(colidx + e + 8);
        float w0 = dinv[s0] * di;
        float w1 = dinv[s1] * di;
        acc0 += w0 * zp[(size_t)s0 * zstride + c];
        acc1 += w1 * zp[(size_t)s1 * zstride + c];
    }
    if (e < end) {
        int s0 = __builtin_nontemporal_load(colidx + e);
        acc0 += dinv[s0] * di * zp[(size_t)s0 * zstride + c];
        e += 8;
        if (e < end) {
            int s1 = __builtin_nontemporal_load(colidx + e);
            acc1 += dinv[s1] * di * zp[(size_t)s1 * zstride + c];
        }
    }
    float acc = acc0 + acc1;
    acc += __shfl_xor(acc, 8);
    acc += __shfl_xor(acc, 16);
    acc += __shfl_xor(acc, 32);
    if (lane < 8) {
        float hv = __builtin_nontemporal_load(hp + (size_t)i * 8 + c);
        op[(size_t)i * ostride + c] = (1.0f - PROP_ALPHA) * acc + PROP_ALPHA * hv;
    }
}

// ---------------- launch ----------------

extern "C" void kernel_launch(void* const* d_in, const int* in_sizes, int n_in,
                              void* d_out, int out_size, void* d_ws, size_t ws_size,
                              hipStream_t stream) {
    const float* x  = (const float*)d_in[0];
    const int*   ei = (const int*)d_in[1];
    const float* W3 = (const float*)d_in[2];
    const float* b3 = (const float*)d_in[3];
    const float* W4 = (const float*)d_in[4];
    const float* b4 = (const float*)d_in[5];
    float* out = (float*)d_out;

    int N = in_sizes[0] / 64;   // IN_CH = 64
    int E = in_sizes[1] / 2;
    const int* srcA = ei;
    const int* dstA = ei + E;

    char* ws = (char*)d_ws;
    size_t off = 0;
    auto alloc = [&](size_t bytes) -> void* {
        void* p = ws + off;
        off = (off + bytes + 255) & ~(size_t)255;
        return p;
    };

    int nScanB = (N + 255) / 256;

    int*   degI   = (int*)alloc((size_t)N * 4);
    int*   rowptr = (int*)alloc(((size_t)N + 1) * 4);
    int*   rowctr = (int*)alloc((size_t)N * 4);
    int*   bsums  = (int*)alloc((size_t)nScanB * 4);
    float* dinv   = (float*)alloc((size_t)N * 4);
    int*   colidx = (int*)alloc((size_t)E * 4);
    float* vA     = (float*)alloc((size_t)N * 4);
    float* vB     = (float*)alloc((size_t)N * 4);
    float* zA     = (float*)alloc((size_t)N * 64 * 4);   // chunked [8][N][8]
    float* zB     = (float*)alloc((size_t)N * 64 * 4);   // chunked
    float* zxs    = (float*)alloc((size_t)N * 64 * 4);   // strided [N][64]
    float* hbuf   = (float*)alloc((size_t)N * 64 * 4);   // strided
    float* hxc    = (float*)alloc((size_t)N * 64 * 4);   // chunked copy of x
    float* hbc    = (float*)alloc((size_t)N * 64 * 4);   // chunked copy of hbuf

    hipMemsetAsync(degI, 0, (size_t)N * 4, stream);
    hipMemsetAsync(rowctr, 0, (size_t)N * 4, stream);

    // --- CSR build ---
    hist_kernel<<<(E + 255) / 256, 256, 0, stream>>>(dstA, degI, E);
    dinv_kernel<<<(N + 255) / 256, 256, 0, stream>>>(degI, dinv, N);
    scan1_kernel<<<nScanB, 256, 0, stream>>>(degI, rowptr, bsums, N);
    scan2_kernel<<<1, 256, 0, stream>>>(bsums, nScanB);
    scan3_kernel<<<nScanB, 256, 0, stream>>>(rowptr, bsums, N);
    scatter_kernel<<<(E + 255) / 256, 256, 0, stream>>>(srcA, dstA, rowptr, rowctr,
                                                        colidx, E);

    int bpc = (N + 3) / 4;            // node-blocks per chunk
    int propGrid = bpc * 8;           // 8 chunks interleaved via blockIdx&7
    long chunkedPitch = (long)N * 8;
    dim3 rcGrid((N * 8 + 255) / 256, 8);

    // --- v = M * ones ---
    for (int s = 0; s < PROP_KSTEPS; ++s) {
        const float* in = (s == 0) ? vA /*unused*/ : ((s & 1) ? vA : vB);
        float*       o  = (s & 1) ? vB : vA;
        propvec_kernel<<<bpc, 256, 0, stream>>>(in, rowptr, colidx, dinv, o, N,
                                                s == 0 ? 1 : 0);
    }
    // final v in vB

    // --- chunked teleport copy of x ---
    rechunk_kernel<<<rcGrid, 256, 0, stream>>>(x, hxc, N);

    // --- zx = M * x : XCD-pinned chunked prop; step0 reads x strided,
    //     step9 writes zxs strided ---
    for (int s = 0; s < PROP_KSTEPS; ++s) {
        const float* in;  long zp; int zs_;
        float* o;         long op; int os_;
        if (s == 0) { in = x; zp = 8; zs_ = 64; }
        else        { in = ((s & 1) == 1) ? zA : zB; zp = chunkedPitch; zs_ = 8; }
        if (s == PROP_KSTEPS - 1) { o = zxs; op = 8; os_ = 64; }
        else { o = ((s & 1) == 0) ? zA : zB; op = chunkedPitch; os_ = 8; }
        prop8_kernel<<<propGrid, 256, 0, stream>>>(in, zp, zs_, hxc, rowptr, colidx,
                                                   dinv, o, op, os_, N);
    }

    // --- h2 = relu(zx@W3 + v*b3^T)@W4 + b4 ---
    fusedmlp_kernel<<<(N + 31) / 32, 256, 0, stream>>>(zxs, vB, W3, b3, W4, b4, hbuf, N);

    // --- chunked teleport copy of hbuf ---
    rechunk_kernel<<<rcGrid, 256, 0, stream>>>(hbuf, hbc, N);

    // --- out = M * h2 : step0 reads hbuf strided, step9 writes d_out strided ---
    for (int s = 0; s < PROP_KSTEPS; ++s) {
        const float* in;  long zp; int zs_;
        float* o;         long op; int os_;
        if (s == 0) { in = hbuf; zp = 8; zs_ = 64; }
        else        { in = ((s & 1) == 1) ? zA : zB; zp = chunkedPitch; zs_ = 8; }
        if (s == PROP_KSTEPS - 1) { o = out; op = 8; os_ = 64; }
        else { o = ((s & 1) == 0) ? zA : zB; op = chunkedPitch; os_ = 8; }
        prop8_kernel<<<propGrid, 256, 0, stream>>>(in, zp, zs_, hbc, rowptr, colidx,
                                                   dinv, o, op, os_, N);
    }
}

// Round 6
// 1110.464 us; speedup vs baseline: 2.8351x; 2.8351x over previous
//
#include <hip/hip_runtime.h>

#define PROP_ALPHA 0.1f
#define PROP_KSTEPS 10

// ---------------- CSR build ----------------

__global__ void hist_kernel(const int* __restrict__ dst, int* __restrict__ degI, int E) {
    int e = blockIdx.x * blockDim.x + threadIdx.x;
    if (e < E) atomicAdd(&degI[dst[e]], 1);
}

__global__ void dinv_kernel(const int* __restrict__ degI, float* __restrict__ dinv, int N) {
    int i = blockIdx.x * blockDim.x + threadIdx.x;
    if (i < N) {
        float d = (float)(degI[i] + 1);   // + self loop
        dinv[i] = rsqrtf(d);
    }
}

// ---- 3-kernel device-wide exclusive scan ----

__global__ __launch_bounds__(256) void scan1_kernel(const int* __restrict__ degI,
                                                    int* __restrict__ rowptr,
                                                    int* __restrict__ blockSums, int N) {
    __shared__ int s[256];
    int t = threadIdx.x;
    int idx = blockIdx.x * 256 + t;
    s[t] = (idx < N) ? degI[idx] : 0;
    __syncthreads();
    for (int off = 1; off < 256; off <<= 1) {
        int x = (t >= off) ? s[t - off] : 0;
        __syncthreads();
        s[t] += x;
        __syncthreads();
    }
    if (idx < N) rowptr[idx + 1] = s[t];
    if (t == 255) blockSums[blockIdx.x] = s[255];
    if (blockIdx.x == 0 && t == 0) rowptr[0] = 0;
}

__global__ __launch_bounds__(256) void scan2_kernel(int* __restrict__ blockSums, int nB) {
    __shared__ int s[256];
    int t = threadIdx.x;
    s[t] = (t < nB) ? blockSums[t] : 0;
    __syncthreads();
    for (int off = 1; off < 256; off <<= 1) {
        int x = (t >= off) ? s[t - off] : 0;
        __syncthreads();
        s[t] += x;
        __syncthreads();
    }
    if (t < nB) blockSums[t] = (t == 0) ? 0 : s[t - 1];
}

__global__ void scan3_kernel(int* __restrict__ rowptr, const int* __restrict__ blockSums,
                             int N) {
    int idx = blockIdx.x * 256 + threadIdx.x;
    if (idx < N) rowptr[idx + 1] += blockSums[blockIdx.x];
}

// edata[p] = { src, bitcast(norm) }
__global__ void scatter_kernel(const int* __restrict__ src, const int* __restrict__ dst,
                               const int* __restrict__ rowptr, int* __restrict__ rowctr,
                               const float* __restrict__ dinv,
                               int2* __restrict__ edata, int E) {
    int e = blockIdx.x * blockDim.x + threadIdx.x;
    if (e < E) {
        int d = dst[e], s = src[e];
        int p = rowptr[d] + atomicAdd(&rowctr[d], 1);
        int2 ed;
        ed.x = s;
        ed.y = __float_as_int(dinv[s] * dinv[d]);
        edata[p] = ed;
    }
}

// ---------------- fused MLP: h2 = relu(zx@W3 + v*b3^T)@W4 + b4 ----------------
// Register-tiled from LDS: layer1 4x4 tiles (256 thr = 8 row-grp x 32 col-grp),
// layer2 2x4 tiles (16 row-grp x 16 col-grp). Ws (32 KB) reused for W3 then W4.

__global__ __launch_bounds__(256) void fusedmlp_kernel(const float* __restrict__ zx,
                                                       const float* __restrict__ v,
                                                       const float* __restrict__ W3,
                                                       const float* __restrict__ b3,
                                                       const float* __restrict__ W4,
                                                       const float* __restrict__ b4,
                                                       float* __restrict__ h2, int N) {
    __shared__ float Ws[64 * 128];    // 32 KB: W3 [k][128] then W4 [k][64]
    __shared__ float zsT[64 * 36];    // [k][row] transposed, padded
    __shared__ float tsT[128 * 36];   // [k][row]
    __shared__ float vs[32];
    int t = threadIdx.x;
    int r0 = blockIdx.x * 32;
    int rows = min(32, N - r0);

    // stage W3 + z (transposed, zero-padded) + v
    for (int idx = t; idx < 64 * 128; idx += 256) Ws[idx] = W3[idx];
    for (int idx = t; idx < 32 * 64; idx += 256) {
        int r = idx >> 6, c = idx & 63;
        zsT[c * 36 + r] = (r < rows) ? zx[(size_t)(r0 + r) * 64 + c] : 0.0f;
    }
    if (t < 32) vs[t] = (t < rows) ? v[r0 + t] : 0.0f;
    __syncthreads();

    // ---- layer 1: tsT = relu(z @ W3 + v*b3^T): 32 rows x 128 cols ----
    {
        int cq = t & 31, rq = t >> 5;     // col group (4 cols), row group (4 rows)
        int cb = cq * 4, rb = rq * 4;
        float4 b3v = *reinterpret_cast<const float4*>(&b3[cb]);
        float a[4][4];
        #pragma unroll
        for (int ri = 0; ri < 4; ++ri) {
            float vv = vs[rb + ri];
            a[ri][0] = vv * b3v.x; a[ri][1] = vv * b3v.y;
            a[ri][2] = vv * b3v.z; a[ri][3] = vv * b3v.w;
        }
        #pragma unroll 4
        for (int k = 0; k < 64; ++k) {
            float4 zq = *reinterpret_cast<const float4*>(&zsT[k * 36 + rb]);
            float4 wq = *reinterpret_cast<const float4*>(&Ws[k * 128 + cb]);
            a[0][0] += zq.x * wq.x; a[0][1] += zq.x * wq.y;
            a[0][2] += zq.x * wq.z; a[0][3] += zq.x * wq.w;
            a[1][0] += zq.y * wq.x; a[1][1] += zq.y * wq.y;
            a[1][2] += zq.y * wq.z; a[1][3] += zq.y * wq.w;
            a[2][0] += zq.z * wq.x; a[2][1] += zq.z * wq.y;
            a[2][2] += zq.z * wq.z; a[2][3] += zq.z * wq.w;
            a[3][0] += zq.w * wq.x; a[3][1] += zq.w * wq.y;
            a[3][2] += zq.w * wq.z; a[3][3] += zq.w * wq.w;
        }
        #pragma unroll
        for (int ci = 0; ci < 4; ++ci) {
            float4 o;
            o.x = fmaxf(a[0][ci], 0.0f); o.y = fmaxf(a[1][ci], 0.0f);
            o.z = fmaxf(a[2][ci], 0.0f); o.w = fmaxf(a[3][ci], 0.0f);
            *reinterpret_cast<float4*>(&tsT[(cb + ci) * 36 + rb]) = o;
        }
    }
    __syncthreads();
    for (int idx = t; idx < 128 * 64; idx += 256) Ws[idx] = W4[idx];
    __syncthreads();

    // ---- layer 2: h2 = t @ W4 + b4: 32 rows x 64 cols ----
    {
        int cg = t & 15, rg = t >> 4;     // col group (4), row group (2)
        int cb = cg * 4, rb = rg * 2;
        float4 b4v = *reinterpret_cast<const float4*>(&b4[cb]);
        float a[2][4];
        #pragma unroll
        for (int ri = 0; ri < 2; ++ri) {
            a[ri][0] = b4v.x; a[ri][1] = b4v.y; a[ri][2] = b4v.z; a[ri][3] = b4v.w;
        }
        #pragma unroll 4
        for (int k = 0; k < 128; ++k) {
            float2 zq = *reinterpret_cast<const float2*>(&tsT[k * 36 + rb]);
            float4 wq = *reinterpret_cast<const float4*>(&Ws[k * 64 + cb]);
            a[0][0] += zq.x * wq.x; a[0][1] += zq.x * wq.y;
            a[0][2] += zq.x * wq.z; a[0][3] += zq.x * wq.w;
            a[1][0] += zq.y * wq.x; a[1][1] += zq.y * wq.y;
            a[1][2] += zq.y * wq.z; a[1][3] += zq.y * wq.w;
        }
        #pragma unroll
        for (int ri = 0; ri < 2; ++ri) {
            int r = rb + ri;
            if (r < rows) {
                float4 o = {a[ri][0], a[ri][1], a[ri][2], a[ri][3]};
                *reinterpret_cast<float4*>(&h2[(size_t)(r0 + r) * 64 + cb]) = o;
            }
        }
    }
}

// ---------------- propagation ----------------
// z-prop: wave = 1 node, 16 lanes x float4 per row, 4 edge-groups -> 1 KB/gather instr.
// Trailing blocks (bid >= propBlocks) run one ones-vector step (thread per node),
// fusing propvec into the same dispatch (prop1 only).

__global__ __launch_bounds__(256) void prop_kernel(const float* __restrict__ zin,
                                                   const float* __restrict__ h,
                                                   const int* __restrict__ rowptr,
                                                   const int2* __restrict__ edata,
                                                   const float* __restrict__ dinv,
                                                   float* __restrict__ zout,
                                                   const float* __restrict__ vin,
                                                   float* __restrict__ vout,
                                                   int N, int propBlocks, int firstOnes) {
    int bid = blockIdx.x;
    if (bid >= propBlocks) {
        // ---- ones-vector step, thread per node ----
        int i = (bid - propBlocks) * 256 + threadIdx.x;
        if (i < N) {
            int beg = rowptr[i], end = rowptr[i + 1];
            float di = dinv[i];
            float self = firstOnes ? 1.0f : vin[i];
            float acc = di * di * self;
            for (int e = beg; e < end; ++e) {
                int2 ed = edata[e];
                acc += __int_as_float(ed.y) * (firstOnes ? 1.0f : vin[ed.x]);
            }
            vout[i] = (1.0f - PROP_ALPHA) * acc + PROP_ALPHA;
        }
        return;
    }
    int wave = threadIdx.x >> 6, lane = threadIdx.x & 63;
    int eg = lane >> 4, c4 = lane & 15;     // edge group, channel quad
    int i = bid * 4 + wave;
    if (i >= N) return;
    i = __builtin_amdgcn_readfirstlane(i);
    int beg = rowptr[i], end = rowptr[i + 1];
    float di = dinv[i];
    const float4* z4 = (const float4*)zin;
    size_t li = (size_t)i * 16 + c4;

    float4 acc0 = {0.0f, 0.0f, 0.0f, 0.0f};
    float4 acc1 = {0.0f, 0.0f, 0.0f, 0.0f};
    if (eg == 0) {
        float w0 = di * di;
        float4 zi = z4[li];
        acc0.x = w0 * zi.x; acc0.y = w0 * zi.y; acc0.z = w0 * zi.z; acc0.w = w0 * zi.w;
    }
    const long long* ed8 = (const long long*)edata;
    int e = beg + eg;
    for (; e + 4 < end; e += 8) {
        long long p0 = __builtin_nontemporal_load(ed8 + e);
        long long p1 = __builtin_nontemporal_load(ed8 + e + 4);
        int s0 = (int)p0;  float w0 = __int_as_float((int)(p0 >> 32));
        int s1 = (int)p1;  float w1 = __int_as_float((int)(p1 >> 32));
        float4 v0 = z4[(size_t)s0 * 16 + c4];
        float4 v1 = z4[(size_t)s1 * 16 + c4];
        acc0.x += w0 * v0.x; acc0.y += w0 * v0.y; acc0.z += w0 * v0.z; acc0.w += w0 * v0.w;
        acc1.x += w1 * v1.x; acc1.y += w1 * v1.y; acc1.z += w1 * v1.z; acc1.w += w1 * v1.w;
    }
    if (e < end) {
        long long p0 = __builtin_nontemporal_load(ed8 + e);
        int s0 = (int)p0;  float w0 = __int_as_float((int)(p0 >> 32));
        float4 v0 = z4[(size_t)s0 * 16 + c4];
        acc0.x += w0 * v0.x; acc0.y += w0 * v0.y; acc0.z += w0 * v0.z; acc0.w += w0 * v0.w;
    }
    acc0.x += acc1.x; acc0.y += acc1.y; acc0.z += acc1.z; acc0.w += acc1.w;
    // reduce across the 4 edge groups
    acc0.x += __shfl_xor(acc0.x, 16); acc0.y += __shfl_xor(acc0.y, 16);
    acc0.z += __shfl_xor(acc0.z, 16); acc0.w += __shfl_xor(acc0.w, 16);
    acc0.x += __shfl_xor(acc0.x, 32); acc0.y += __shfl_xor(acc0.y, 32);
    acc0.z += __shfl_xor(acc0.z, 32); acc0.w += __shfl_xor(acc0.w, 32);
    if (lane < 16) {
        float4 hv = ((const float4*)h)[li];
        float4 o;
        o.x = (1.0f - PROP_ALPHA) * acc0.x + PROP_ALPHA * hv.x;
        o.y = (1.0f - PROP_ALPHA) * acc0.y + PROP_ALPHA * hv.y;
        o.z = (1.0f - PROP_ALPHA) * acc0.z + PROP_ALPHA * hv.z;
        o.w = (1.0f - PROP_ALPHA) * acc0.w + PROP_ALPHA * hv.w;
        ((float4*)zout)[li] = o;
    }
}

// ---------------- launch ----------------

extern "C" void kernel_launch(void* const* d_in, const int* in_sizes, int n_in,
                              void* d_out, int out_size, void* d_ws, size_t ws_size,
                              hipStream_t stream) {
    const float* x  = (const float*)d_in[0];
    const int*   ei = (const int*)d_in[1];
    const float* W3 = (const float*)d_in[2];
    const float* b3 = (const float*)d_in[3];
    const float* W4 = (const float*)d_in[4];
    const float* b4 = (const float*)d_in[5];
    float* out = (float*)d_out;

    int N = in_sizes[0] / 64;   // IN_CH = 64
    int E = in_sizes[1] / 2;
    const int* srcA = ei;
    const int* dstA = ei + E;

    char* ws = (char*)d_ws;
    size_t off = 0;
    auto alloc = [&](size_t bytes) -> void* {
        void* p = ws + off;
        off = (off + bytes + 255) & ~(size_t)255;
        return p;
    };

    int nScanB = (N + 255) / 256;

    int*   degI   = (int*)alloc((size_t)N * 4);
    int*   rowptr = (int*)alloc(((size_t)N + 1) * 4);
    int*   rowctr = (int*)alloc((size_t)N * 4);
    int*   bsums  = (int*)alloc((size_t)nScanB * 4);
    float* dinv   = (float*)alloc((size_t)N * 4);
    int2*  edata  = (int2*)alloc((size_t)E * 8);
    float* vA     = (float*)alloc((size_t)N * 4);
    float* vB     = (float*)alloc((size_t)N * 4);
    float* zA     = (float*)alloc((size_t)N * 64 * 4);
    float* zB     = (float*)alloc((size_t)N * 64 * 4);
    float* hbuf   = (float*)alloc((size_t)N * 64 * 4);

    hipMemsetAsync(degI, 0, (size_t)N * 4, stream);
    hipMemsetAsync(rowctr, 0, (size_t)N * 4, stream);

    // --- CSR build ---
    hist_kernel<<<(E + 255) / 256, 256, 0, stream>>>(dstA, degI, E);
    dinv_kernel<<<(N + 255) / 256, 256, 0, stream>>>(degI, dinv, N);
    scan1_kernel<<<nScanB, 256, 0, stream>>>(degI, rowptr, bsums, N);
    scan2_kernel<<<1, 256, 0, stream>>>(bsums, nScanB);
    scan3_kernel<<<nScanB, 256, 0, stream>>>(rowptr, bsums, N);
    scatter_kernel<<<(E + 255) / 256, 256, 0, stream>>>(srcA, dstA, rowptr, rowctr,
                                                        dinv, edata, E);

    int propBlocks = (N + 3) / 4;

    // --- prop1 (zx = M*x) with fused v = M*ones in trailing blocks ---
    for (int s = 0; s < PROP_KSTEPS; ++s) {
        const float* in = (s == 0) ? x : ((s & 1) ? zA : zB);
        float*       o  = (s & 1) ? zB : zA;        // step9 -> zB
        const float* vi = (s & 1) ? vA : vB;        // unused when s==0
        float*       vo = (s & 1) ? vB : vA;        // step9 -> vB
        if (s == 0) vi = vA;
        prop_kernel<<<propBlocks + nScanB, 256, 0, stream>>>(
            in, x, rowptr, edata, dinv, o, vi, vo, N, propBlocks, s == 0 ? 1 : 0);
    }
    // zx in zB, v in vB

    // --- h2 = relu(zx@W3 + v*b3^T)@W4 + b4 ---
    fusedmlp_kernel<<<(N + 31) / 32, 256, 0, stream>>>(zB, vB, W3, b3, W4, b4, hbuf, N);

    // --- prop2 (out = M*h2), no v work ---
    for (int s = 0; s < PROP_KSTEPS; ++s) {
        const float* in = (s == 0) ? hbuf : ((s & 1) ? zA : zB);
        float*       o  = (s == PROP_KSTEPS - 1) ? out : ((s & 1) ? zB : zA);
        prop_kernel<<<propBlocks, 256, 0, stream>>>(
            in, hbuf, rowptr, edata, dinv, o, nullptr, nullptr, N, propBlocks, 0);
    }
}

// Round 7
// 924.896 us; speedup vs baseline: 3.4039x; 1.2006x over previous
//
#include <hip/hip_runtime.h>

#define PROP_ALPHA 0.1f
#define PROP_KSTEPS 10

// ---------------- CSR build ----------------

__global__ void hist_kernel(const int* __restrict__ dst, int* __restrict__ degI, int E) {
    int e = blockIdx.x * blockDim.x + threadIdx.x;
    if (e < E) atomicAdd(&degI[dst[e]], 1);
}

__global__ void dinv_kernel(const int* __restrict__ degI, float* __restrict__ dinv, int N) {
    int i = blockIdx.x * blockDim.x + threadIdx.x;
    if (i < N) {
        float d = (float)(degI[i] + 1);   // + self loop
        dinv[i] = rsqrtf(d);
    }
}

// ---- 3-kernel device-wide exclusive scan ----

__global__ __launch_bounds__(256) void scan1_kernel(const int* __restrict__ degI,
                                                    int* __restrict__ rowptr,
                                                    int* __restrict__ blockSums, int N) {
    __shared__ int s[256];
    int t = threadIdx.x;
    int idx = blockIdx.x * 256 + t;
    s[t] = (idx < N) ? degI[idx] : 0;
    __syncthreads();
    for (int off = 1; off < 256; off <<= 1) {
        int x = (t >= off) ? s[t - off] : 0;
        __syncthreads();
        s[t] += x;
        __syncthreads();
    }
    if (idx < N) rowptr[idx + 1] = s[t];
    if (t == 255) blockSums[blockIdx.x] = s[255];
    if (blockIdx.x == 0 && t == 0) rowptr[0] = 0;
}

__global__ __launch_bounds__(256) void scan2_kernel(int* __restrict__ blockSums, int nB) {
    __shared__ int s[256];
    int t = threadIdx.x;
    s[t] = (t < nB) ? blockSums[t] : 0;
    __syncthreads();
    for (int off = 1; off < 256; off <<= 1) {
        int x = (t >= off) ? s[t - off] : 0;
        __syncthreads();
        s[t] += x;
        __syncthreads();
    }
    if (t < nB) blockSums[t] = (t == 0) ? 0 : s[t - 1];
}

__global__ void scan3_kernel(int* __restrict__ rowptr, const int* __restrict__ blockSums,
                             int N) {
    int idx = blockIdx.x * 256 + threadIdx.x;
    if (idx < N) rowptr[idx + 1] += blockSums[blockIdx.x];
}

__global__ void scatter_kernel(const int* __restrict__ src, const int* __restrict__ dst,
                               const int* __restrict__ rowptr, int* __restrict__ rowctr,
                               const float* __restrict__ dinv,
                               int* __restrict__ colidx, float* __restrict__ normv, int E) {
    int e = blockIdx.x * blockDim.x + threadIdx.x;
    if (e < E) {
        int d = dst[e], s = src[e];
        int p = rowptr[d] + atomicAdd(&rowctr[d], 1);
        colidx[p] = s;
        normv[p] = dinv[s] * dinv[d];
    }
}

// ---------------- fused MLP: h2 = relu(zx@W3 + v*b3^T)@W4 + b4 ----------------
// Register-tiled from LDS (validated R6): layer1 4x4 tiles, layer2 2x4 tiles.
// Ws (32 KB) reused for W3 then W4; z/t transposed for broadcast b128 reads.

__global__ __launch_bounds__(256) void fusedmlp_kernel(const float* __restrict__ zx,
                                                       const float* __restrict__ v,
                                                       const float* __restrict__ W3,
                                                       const float* __restrict__ b3,
                                                       const float* __restrict__ W4,
                                                       const float* __restrict__ b4,
                                                       float* __restrict__ h2, int N) {
    __shared__ float Ws[64 * 128];    // 32 KB: W3 [k][128] then W4 [k][64]
    __shared__ float zsT[64 * 36];    // [k][row] transposed, padded
    __shared__ float tsT[128 * 36];   // [k][row]
    __shared__ float vs[32];
    int t = threadIdx.x;
    int r0 = blockIdx.x * 32;
    int rows = min(32, N - r0);

    for (int idx = t; idx < 64 * 128; idx += 256) Ws[idx] = W3[idx];
    for (int idx = t; idx < 32 * 64; idx += 256) {
        int r = idx >> 6, c = idx & 63;
        zsT[c * 36 + r] = (r < rows) ? zx[(size_t)(r0 + r) * 64 + c] : 0.0f;
    }
    if (t < 32) vs[t] = (t < rows) ? v[r0 + t] : 0.0f;
    __syncthreads();

    // ---- layer 1: tsT = relu(z @ W3 + v*b3^T): 32 rows x 128 cols ----
    {
        int cq = t & 31, rq = t >> 5;
        int cb = cq * 4, rb = rq * 4;
        float4 b3v = *reinterpret_cast<const float4*>(&b3[cb]);
        float a[4][4];
        #pragma unroll
        for (int ri = 0; ri < 4; ++ri) {
            float vv = vs[rb + ri];
            a[ri][0] = vv * b3v.x; a[ri][1] = vv * b3v.y;
            a[ri][2] = vv * b3v.z; a[ri][3] = vv * b3v.w;
        }
        #pragma unroll 4
        for (int k = 0; k < 64; ++k) {
            float4 zq = *reinterpret_cast<const float4*>(&zsT[k * 36 + rb]);
            float4 wq = *reinterpret_cast<const float4*>(&Ws[k * 128 + cb]);
            a[0][0] += zq.x * wq.x; a[0][1] += zq.x * wq.y;
            a[0][2] += zq.x * wq.z; a[0][3] += zq.x * wq.w;
            a[1][0] += zq.y * wq.x; a[1][1] += zq.y * wq.y;
            a[1][2] += zq.y * wq.z; a[1][3] += zq.y * wq.w;
            a[2][0] += zq.z * wq.x; a[2][1] += zq.z * wq.y;
            a[2][2] += zq.z * wq.z; a[2][3] += zq.z * wq.w;
            a[3][0] += zq.w * wq.x; a[3][1] += zq.w * wq.y;
            a[3][2] += zq.w * wq.z; a[3][3] += zq.w * wq.w;
        }
        #pragma unroll
        for (int ci = 0; ci < 4; ++ci) {
            float4 o;
            o.x = fmaxf(a[0][ci], 0.0f); o.y = fmaxf(a[1][ci], 0.0f);
            o.z = fmaxf(a[2][ci], 0.0f); o.w = fmaxf(a[3][ci], 0.0f);
            *reinterpret_cast<float4*>(&tsT[(cb + ci) * 36 + rb]) = o;
        }
    }
    __syncthreads();
    for (int idx = t; idx < 128 * 64; idx += 256) Ws[idx] = W4[idx];
    __syncthreads();

    // ---- layer 2: h2 = t @ W4 + b4: 32 rows x 64 cols ----
    {
        int cg = t & 15, rg = t >> 4;
        int cb = cg * 4, rb = rg * 2;
        float4 b4v = *reinterpret_cast<const float4*>(&b4[cb]);
        float a[2][4];
        #pragma unroll
        for (int ri = 0; ri < 2; ++ri) {
            a[ri][0] = b4v.x; a[ri][1] = b4v.y; a[ri][2] = b4v.z; a[ri][3] = b4v.w;
        }
        #pragma unroll 4
        for (int k = 0; k < 128; ++k) {
            float2 zq = *reinterpret_cast<const float2*>(&tsT[k * 36 + rb]);
            float4 wq = *reinterpret_cast<const float4*>(&Ws[k * 64 + cb]);
            a[0][0] += zq.x * wq.x; a[0][1] += zq.x * wq.y;
            a[0][2] += zq.x * wq.z; a[0][3] += zq.x * wq.w;
            a[1][0] += zq.y * wq.x; a[1][1] += zq.y * wq.y;
            a[1][2] += zq.y * wq.z; a[1][3] += zq.y * wq.w;
        }
        #pragma unroll
        for (int ri = 0; ri < 2; ++ri) {
            int r = rb + ri;
            if (r < rows) {
                float4 o = {a[ri][0], a[ri][1], a[ri][2], a[ri][3]};
                *reinterpret_cast<float4*>(&h2[(size_t)(r0 + r) * 64 + cb]) = o;
            }
        }
    }
}

// ---------------- propagation ----------------
// R3's proven scalar kernel: wave per node, lane = channel, 1 edge per gather
// instr (256 B row), unroll x8 with 4 accumulators. WITHV additionally
// propagates the ones-vector v: per edge all lanes load vin[src] at the SAME
// address (single broadcast L2-hit request, v = 200 KB L2-resident) and
// redundantly accumulate; lane 0 writes vout.

template <bool WITHV>
__global__ __launch_bounds__(256) void prop64_kernel(const float* __restrict__ zin,
                                                     const float* __restrict__ h,
                                                     const int* __restrict__ rowptr,
                                                     const int* __restrict__ colidx,
                                                     const float* __restrict__ normv,
                                                     const float* __restrict__ dinv,
                                                     float* __restrict__ zout,
                                                     const float* __restrict__ vin,
                                                     float* __restrict__ vout,
                                                     int N, int firstOnes) {
    int wave = threadIdx.x >> 6;
    int lane = threadIdx.x & 63;
    int i = blockIdx.x * 4 + wave;
    if (i >= N) return;
    i = __builtin_amdgcn_readfirstlane(i);   // wave-uniform -> scalar CSR loads
    int beg = rowptr[i], end = rowptr[i + 1];
    float di = dinv[i];
    size_t li = (size_t)i * 64 + lane;
    float acc0 = di * di * zin[li];
    float acc1 = 0.0f, acc2 = 0.0f, acc3 = 0.0f;
    float vacc = 0.0f;
    int e = beg;
    for (; e + 8 <= end; e += 8) {
        int s0 = colidx[e],     s1 = colidx[e + 1], s2 = colidx[e + 2], s3 = colidx[e + 3];
        int s4 = colidx[e + 4], s5 = colidx[e + 5], s6 = colidx[e + 6], s7 = colidx[e + 7];
        float n0 = normv[e],     n1 = normv[e + 1], n2 = normv[e + 2], n3 = normv[e + 3];
        float n4 = normv[e + 4], n5 = normv[e + 5], n6 = normv[e + 6], n7 = normv[e + 7];
        float v0 = zin[(size_t)s0 * 64 + lane];
        float v1 = zin[(size_t)s1 * 64 + lane];
        float v2 = zin[(size_t)s2 * 64 + lane];
        float v3 = zin[(size_t)s3 * 64 + lane];
        float v4 = zin[(size_t)s4 * 64 + lane];
        float v5 = zin[(size_t)s5 * 64 + lane];
        float v6 = zin[(size_t)s6 * 64 + lane];
        float v7 = zin[(size_t)s7 * 64 + lane];
        if (WITHV) {
            if (firstOnes) {
                vacc += (n0 + n1 + n2 + n3) + (n4 + n5 + n6 + n7);
            } else {
                vacc += n0 * vin[s0] + n1 * vin[s1] + n2 * vin[s2] + n3 * vin[s3]
                      + n4 * vin[s4] + n5 * vin[s5] + n6 * vin[s6] + n7 * vin[s7];
            }
        }
        acc0 += n0 * v0; acc1 += n1 * v1; acc2 += n2 * v2; acc3 += n3 * v3;
        acc0 += n4 * v4; acc1 += n5 * v5; acc2 += n6 * v6; acc3 += n7 * v7;
    }
    for (; e < end; ++e) {
        int s = colidx[e];
        float n = normv[e];
        acc0 += n * zin[(size_t)s * 64 + lane];
        if (WITHV) vacc += n * (firstOnes ? 1.0f : vin[s]);
    }
    float acc = (acc0 + acc1) + (acc2 + acc3);
    float hv = h[li];
    zout[li] = (1.0f - PROP_ALPHA) * acc + PROP_ALPHA * hv;
    if (WITHV) {
        if (lane == 0) {
            float selfv = firstOnes ? 1.0f : vin[i];
            vout[i] = (1.0f - PROP_ALPHA) * (vacc + di * di * selfv) + PROP_ALPHA;
        }
    }
}

// ---------------- launch ----------------

extern "C" void kernel_launch(void* const* d_in, const int* in_sizes, int n_in,
                              void* d_out, int out_size, void* d_ws, size_t ws_size,
                              hipStream_t stream) {
    const float* x  = (const float*)d_in[0];
    const int*   ei = (const int*)d_in[1];
    const float* W3 = (const float*)d_in[2];
    const float* b3 = (const float*)d_in[3];
    const float* W4 = (const float*)d_in[4];
    const float* b4 = (const float*)d_in[5];
    float* out = (float*)d_out;

    int N = in_sizes[0] / 64;   // IN_CH = 64
    int E = in_sizes[1] / 2;
    const int* srcA = ei;
    const int* dstA = ei + E;

    char* ws = (char*)d_ws;
    size_t off = 0;
    auto alloc = [&](size_t bytes) -> void* {
        void* p = ws + off;
        off = (off + bytes + 255) & ~(size_t)255;
        return p;
    };

    int nScanB = (N + 255) / 256;

    int*   degI   = (int*)alloc((size_t)N * 4);
    int*   rowptr = (int*)alloc(((size_t)N + 1) * 4);
    int*   rowctr = (int*)alloc((size_t)N * 4);
    int*   bsums  = (int*)alloc((size_t)nScanB * 4);
    float* dinv   = (float*)alloc((size_t)N * 4);
    int*   colidx = (int*)alloc((size_t)E * 4);
    float* normv  = (float*)alloc((size_t)E * 4);
    float* vA     = (float*)alloc((size_t)N * 4);
    float* vB     = (float*)alloc((size_t)N * 4);
    float* zA     = (float*)alloc((size_t)N * 64 * 4);
    float* zB     = (float*)alloc((size_t)N * 64 * 4);
    float* hbuf   = (float*)alloc((size_t)N * 64 * 4);

    hipMemsetAsync(degI, 0, (size_t)N * 4, stream);
    hipMemsetAsync(rowctr, 0, (size_t)N * 4, stream);

    // --- CSR build ---
    hist_kernel<<<(E + 255) / 256, 256, 0, stream>>>(dstA, degI, E);
    dinv_kernel<<<(N + 255) / 256, 256, 0, stream>>>(degI, dinv, N);
    scan1_kernel<<<nScanB, 256, 0, stream>>>(degI, rowptr, bsums, N);
    scan2_kernel<<<1, 256, 0, stream>>>(bsums, nScanB);
    scan3_kernel<<<nScanB, 256, 0, stream>>>(rowptr, bsums, N);
    scatter_kernel<<<(E + 255) / 256, 256, 0, stream>>>(srcA, dstA, rowptr, rowctr,
                                                        dinv, colidx, normv, E);

    int propBlocks = (N + 3) / 4;

    // --- prop1: zx = M*x with fused v = M*ones (broadcast loads) ---
    // parity: step s even writes zA/vA, odd writes zB/vB; step9 -> zB/vB
    for (int s = 0; s < PROP_KSTEPS; ++s) {
        const float* in = (s == 0) ? x : ((s & 1) ? zA : zB);
        float*       o  = (s & 1) ? zB : zA;
        const float* vi = (s & 1) ? vA : vB;   // step0: unused (firstOnes)
        float*       vo = (s & 1) ? vB : vA;
        if (s == 0) vi = vB;                   // any valid pointer
        prop64_kernel<true><<<propBlocks, 256, 0, stream>>>(
            in, x, rowptr, colidx, normv, dinv, o, vi, vo, N, s == 0 ? 1 : 0);
    }
    // zx in zB, v in vB

    // --- h2 = relu(zx@W3 + v*b3^T)@W4 + b4 ---
    fusedmlp_kernel<<<(N + 31) / 32, 256, 0, stream>>>(zB, vB, W3, b3, W4, b4, hbuf, N);

    // --- prop2: out = M*h2 ---
    for (int s = 0; s < PROP_KSTEPS; ++s) {
        const float* in = (s == 0) ? hbuf : ((s & 1) ? zA : zB);
        float*       o  = (s == PROP_KSTEPS - 1) ? out : ((s & 1) ? zB : zA);
        prop64_kernel<false><<<propBlocks, 256, 0, stream>>>(
            in, hbuf, rowptr, colidx, normv, dinv, o, nullptr, nullptr, N, 0);
    }
}

// Round 8
// 860.759 us; speedup vs baseline: 3.6576x; 1.0745x over previous
//
#include <hip/hip_runtime.h>

#define PROP_ALPHA 0.1f
#define PROP_KSTEPS 10

// ---------------- CSR build ----------------

__global__ void hist_kernel(const int* __restrict__ dst, int* __restrict__ degI, int E) {
    int e = blockIdx.x * blockDim.x + threadIdx.x;
    if (e < E) atomicAdd(&degI[dst[e]], 1);
}

__global__ void dinv_kernel(const int* __restrict__ degI, float* __restrict__ dinv, int N) {
    int i = blockIdx.x * blockDim.x + threadIdx.x;
    if (i < N) {
        float d = (float)(degI[i] + 1);   // + self loop
        dinv[i] = rsqrtf(d);
    }
}

// ---- 3-kernel device-wide exclusive scan ----

__global__ __launch_bounds__(256) void scan1_kernel(const int* __restrict__ degI,
                                                    int* __restrict__ rowptr,
                                                    int* __restrict__ blockSums, int N) {
    __shared__ int s[256];
    int t = threadIdx.x;
    int idx = blockIdx.x * 256 + t;
    s[t] = (idx < N) ? degI[idx] : 0;
    __syncthreads();
    for (int off = 1; off < 256; off <<= 1) {
        int x = (t >= off) ? s[t - off] : 0;
        __syncthreads();
        s[t] += x;
        __syncthreads();
    }
    if (idx < N) rowptr[idx + 1] = s[t];
    if (t == 255) blockSums[blockIdx.x] = s[255];
    if (blockIdx.x == 0 && t == 0) rowptr[0] = 0;
}

__global__ __launch_bounds__(256) void scan2_kernel(int* __restrict__ blockSums, int nB) {
    __shared__ int s[256];
    int t = threadIdx.x;
    s[t] = (t < nB) ? blockSums[t] : 0;
    __syncthreads();
    for (int off = 1; off < 256; off <<= 1) {
        int x = (t >= off) ? s[t - off] : 0;
        __syncthreads();
        s[t] += x;
        __syncthreads();
    }
    if (t < nB) blockSums[t] = (t == 0) ? 0 : s[t - 1];
}

__global__ void scan3_kernel(int* __restrict__ rowptr, const int* __restrict__ blockSums,
                             int N) {
    int idx = blockIdx.x * 256 + threadIdx.x;
    if (idx < N) rowptr[idx + 1] += blockSums[blockIdx.x];
}

// edata[p] = { src, bitcast(norm) } — single 8 B store per edge (halves the
// random write-allocate line traffic vs two 4 B stores to separate arrays)
__global__ void scatter_kernel(const int* __restrict__ src, const int* __restrict__ dst,
                               const int* __restrict__ rowptr, int* __restrict__ rowctr,
                               const float* __restrict__ dinv,
                               int2* __restrict__ edata, int E) {
    int e = blockIdx.x * blockDim.x + threadIdx.x;
    if (e < E) {
        int d = dst[e], s = src[e];
        int p = rowptr[d] + atomicAdd(&rowctr[d], 1);
        int2 ed;
        ed.x = s;
        ed.y = __float_as_int(dinv[s] * dinv[d]);
        edata[p] = ed;
    }
}

// ---------------- fused MLP: h2 = relu(zx@W3 + v*b3^T)@W4 + b4 ----------------
// Register-tiled from LDS (validated R6): layer1 4x4 tiles, layer2 2x4 tiles.
// Ws (32 KB) reused for W3 then W4; z/t transposed for broadcast b128 reads.

__global__ __launch_bounds__(256) void fusedmlp_kernel(const float* __restrict__ zx,
                                                       const float* __restrict__ v,
                                                       const float* __restrict__ W3,
                                                       const float* __restrict__ b3,
                                                       const float* __restrict__ W4,
                                                       const float* __restrict__ b4,
                                                       float* __restrict__ h2, int N) {
    __shared__ float Ws[64 * 128];    // 32 KB: W3 [k][128] then W4 [k][64]
    __shared__ float zsT[64 * 36];    // [k][row] transposed, padded
    __shared__ float tsT[128 * 36];   // [k][row]
    __shared__ float vs[32];
    int t = threadIdx.x;
    int r0 = blockIdx.x * 32;
    int rows = min(32, N - r0);

    for (int idx = t; idx < 64 * 128; idx += 256) Ws[idx] = W3[idx];
    for (int idx = t; idx < 32 * 64; idx += 256) {
        int r = idx >> 6, c = idx & 63;
        zsT[c * 36 + r] = (r < rows) ? zx[(size_t)(r0 + r) * 64 + c] : 0.0f;
    }
    if (t < 32) vs[t] = (t < rows) ? v[r0 + t] : 0.0f;
    __syncthreads();

    // ---- layer 1: tsT = relu(z @ W3 + v*b3^T): 32 rows x 128 cols ----
    {
        int cq = t & 31, rq = t >> 5;
        int cb = cq * 4, rb = rq * 4;
        float4 b3v = *reinterpret_cast<const float4*>(&b3[cb]);
        float a[4][4];
        #pragma unroll
        for (int ri = 0; ri < 4; ++ri) {
            float vv = vs[rb + ri];
            a[ri][0] = vv * b3v.x; a[ri][1] = vv * b3v.y;
            a[ri][2] = vv * b3v.z; a[ri][3] = vv * b3v.w;
        }
        #pragma unroll 4
        for (int k = 0; k < 64; ++k) {
            float4 zq = *reinterpret_cast<const float4*>(&zsT[k * 36 + rb]);
            float4 wq = *reinterpret_cast<const float4*>(&Ws[k * 128 + cb]);
            a[0][0] += zq.x * wq.x; a[0][1] += zq.x * wq.y;
            a[0][2] += zq.x * wq.z; a[0][3] += zq.x * wq.w;
            a[1][0] += zq.y * wq.x; a[1][1] += zq.y * wq.y;
            a[1][2] += zq.y * wq.z; a[1][3] += zq.y * wq.w;
            a[2][0] += zq.z * wq.x; a[2][1] += zq.z * wq.y;
            a[2][2] += zq.z * wq.z; a[2][3] += zq.z * wq.w;
            a[3][0] += zq.w * wq.x; a[3][1] += zq.w * wq.y;
            a[3][2] += zq.w * wq.z; a[3][3] += zq.w * wq.w;
        }
        #pragma unroll
        for (int ci = 0; ci < 4; ++ci) {
            float4 o;
            o.x = fmaxf(a[0][ci], 0.0f); o.y = fmaxf(a[1][ci], 0.0f);
            o.z = fmaxf(a[2][ci], 0.0f); o.w = fmaxf(a[3][ci], 0.0f);
            *reinterpret_cast<float4*>(&tsT[(cb + ci) * 36 + rb]) = o;
        }
    }
    __syncthreads();
    for (int idx = t; idx < 128 * 64; idx += 256) Ws[idx] = W4[idx];
    __syncthreads();

    // ---- layer 2: h2 = t @ W4 + b4: 32 rows x 64 cols ----
    {
        int cg = t & 15, rg = t >> 4;
        int cb = cg * 4, rb = rg * 2;
        float4 b4v = *reinterpret_cast<const float4*>(&b4[cb]);
        float a[2][4];
        #pragma unroll
        for (int ri = 0; ri < 2; ++ri) {
            a[ri][0] = b4v.x; a[ri][1] = b4v.y; a[ri][2] = b4v.z; a[ri][3] = b4v.w;
        }
        #pragma unroll 4
        for (int k = 0; k < 128; ++k) {
            float2 zq = *reinterpret_cast<const float2*>(&tsT[k * 36 + rb]);
            float4 wq = *reinterpret_cast<const float4*>(&Ws[k * 64 + cb]);
            a[0][0] += zq.x * wq.x; a[0][1] += zq.x * wq.y;
            a[0][2] += zq.x * wq.z; a[0][3] += zq.x * wq.w;
            a[1][0] += zq.y * wq.x; a[1][1] += zq.y * wq.y;
            a[1][2] += zq.y * wq.z; a[1][3] += zq.y * wq.w;
        }
        #pragma unroll
        for (int ri = 0; ri < 2; ++ri) {
            int r = rb + ri;
            if (r < rows) {
                float4 o = {a[ri][0], a[ri][1], a[ri][2], a[ri][3]};
                *reinterpret_cast<float4*>(&h2[(size_t)(r0 + r) * 64 + cb]) = o;
            }
        }
    }
}

// ---------------- propagation ----------------
// Wave per node, lane = channel, 1 edge per gather instr (256 B contiguous row).
// Main unroll x8 (proven R3 config), then pair-tail so the serialized scalar
// tail is at most 1 edge. WITHV: all lanes load vin[src] at the same address
// (single broadcast L2-hit request), lane 0 writes vout.

template <bool WITHV>
__global__ __launch_bounds__(256) void prop64_kernel(const float* __restrict__ zin,
                                                     const float* __restrict__ h,
                                                     const int* __restrict__ rowptr,
                                                     const int2* __restrict__ edata,
                                                     const float* __restrict__ dinv,
                                                     float* __restrict__ zout,
                                                     const float* __restrict__ vin,
                                                     float* __restrict__ vout,
                                                     int N, int firstOnes) {
    int wave = threadIdx.x >> 6;
    int lane = threadIdx.x & 63;
    int i = blockIdx.x * 4 + wave;
    if (i >= N) return;
    i = __builtin_amdgcn_readfirstlane(i);   // wave-uniform -> scalar CSR loads
    int beg = rowptr[i], end = rowptr[i + 1];
    float di = dinv[i];
    size_t li = (size_t)i * 64 + lane;
    float acc0 = di * di * zin[li];
    float acc1 = 0.0f, acc2 = 0.0f, acc3 = 0.0f;
    float vacc = 0.0f;
    int e = beg;
    for (; e + 8 <= end; e += 8) {
        int2 d0 = edata[e],     d1 = edata[e + 1], d2 = edata[e + 2], d3 = edata[e + 3];
        int2 d4 = edata[e + 4], d5 = edata[e + 5], d6 = edata[e + 6], d7 = edata[e + 7];
        float n0 = __int_as_float(d0.y), n1 = __int_as_float(d1.y);
        float n2 = __int_as_float(d2.y), n3 = __int_as_float(d3.y);
        float n4 = __int_as_float(d4.y), n5 = __int_as_float(d5.y);
        float n6 = __int_as_float(d6.y), n7 = __int_as_float(d7.y);
        float v0 = zin[(size_t)d0.x * 64 + lane];
        float v1 = zin[(size_t)d1.x * 64 + lane];
        float v2 = zin[(size_t)d2.x * 64 + lane];
        float v3 = zin[(size_t)d3.x * 64 + lane];
        float v4 = zin[(size_t)d4.x * 64 + lane];
        float v5 = zin[(size_t)d5.x * 64 + lane];
        float v6 = zin[(size_t)d6.x * 64 + lane];
        float v7 = zin[(size_t)d7.x * 64 + lane];
        if (WITHV) {
            if (firstOnes) {
                vacc += (n0 + n1 + n2 + n3) + (n4 + n5 + n6 + n7);
            } else {
                vacc += n0 * vin[d0.x] + n1 * vin[d1.x] + n2 * vin[d2.x] + n3 * vin[d3.x]
                      + n4 * vin[d4.x] + n5 * vin[d5.x] + n6 * vin[d6.x] + n7 * vin[d7.x];
            }
        }
        acc0 += n0 * v0; acc1 += n1 * v1; acc2 += n2 * v2; acc3 += n3 * v3;
        acc0 += n4 * v4; acc1 += n5 * v5; acc2 += n6 * v6; acc3 += n7 * v7;
    }
    for (; e + 2 <= end; e += 2) {
        int2 d0 = edata[e], d1 = edata[e + 1];
        float n0 = __int_as_float(d0.y), n1 = __int_as_float(d1.y);
        float v0 = zin[(size_t)d0.x * 64 + lane];
        float v1 = zin[(size_t)d1.x * 64 + lane];
        if (WITHV) {
            vacc += firstOnes ? (n0 + n1) : (n0 * vin[d0.x] + n1 * vin[d1.x]);
        }
        acc0 += n0 * v0; acc1 += n1 * v1;
    }
    if (e < end) {
        int2 d0 = edata[e];
        float n0 = __int_as_float(d0.y);
        acc0 += n0 * zin[(size_t)d0.x * 64 + lane];
        if (WITHV) vacc += firstOnes ? n0 : n0 * vin[d0.x];
    }
    float acc = (acc0 + acc1) + (acc2 + acc3);
    float hv = h[li];
    zout[li] = (1.0f - PROP_ALPHA) * acc + PROP_ALPHA * hv;
    if (WITHV) {
        if (lane == 0) {
            float selfv = firstOnes ? 1.0f : vin[i];
            vout[i] = (1.0f - PROP_ALPHA) * (vacc + di * di * selfv) + PROP_ALPHA;
        }
    }
}

// ---------------- launch ----------------

extern "C" void kernel_launch(void* const* d_in, const int* in_sizes, int n_in,
                              void* d_out, int out_size, void* d_ws, size_t ws_size,
                              hipStream_t stream) {
    const float* x  = (const float*)d_in[0];
    const int*   ei = (const int*)d_in[1];
    const float* W3 = (const float*)d_in[2];
    const float* b3 = (const float*)d_in[3];
    const float* W4 = (const float*)d_in[4];
    const float* b4 = (const float*)d_in[5];
    float* out = (float*)d_out;

    int N = in_sizes[0] / 64;   // IN_CH = 64
    int E = in_sizes[1] / 2;
    const int* srcA = ei;
    const int* dstA = ei + E;

    char* ws = (char*)d_ws;
    size_t off = 0;
    auto alloc = [&](size_t bytes) -> void* {
        void* p = ws + off;
        off = (off + bytes + 255) & ~(size_t)255;
        return p;
    };

    int nScanB = (N + 255) / 256;

    int*   degI   = (int*)alloc((size_t)N * 4);
    int*   rowptr = (int*)alloc(((size_t)N + 1) * 4);
    int*   rowctr = (int*)alloc((size_t)N * 4);
    int*   bsums  = (int*)alloc((size_t)nScanB * 4);
    float* dinv   = (float*)alloc((size_t)N * 4);
    int2*  edata  = (int2*)alloc((size_t)E * 8);
    float* vA     = (float*)alloc((size_t)N * 4);
    float* vB     = (float*)alloc((size_t)N * 4);
    float* zA     = (float*)alloc((size_t)N * 64 * 4);
    float* zB     = (float*)alloc((size_t)N * 64 * 4);
    float* hbuf   = (float*)alloc((size_t)N * 64 * 4);

    hipMemsetAsync(degI, 0, (size_t)N * 4, stream);
    hipMemsetAsync(rowctr, 0, (size_t)N * 4, stream);

    // --- CSR build ---
    hist_kernel<<<(E + 255) / 256, 256, 0, stream>>>(dstA, degI, E);
    dinv_kernel<<<(N + 255) / 256, 256, 0, stream>>>(degI, dinv, N);
    scan1_kernel<<<nScanB, 256, 0, stream>>>(degI, rowptr, bsums, N);
    scan2_kernel<<<1, 256, 0, stream>>>(bsums, nScanB);
    scan3_kernel<<<nScanB, 256, 0, stream>>>(rowptr, bsums, N);
    scatter_kernel<<<(E + 255) / 256, 256, 0, stream>>>(srcA, dstA, rowptr, rowctr,
                                                        dinv, edata, E);

    int propBlocks = (N + 3) / 4;

    // --- prop1: zx = M*x with fused v = M*ones (broadcast loads) ---
    for (int s = 0; s < PROP_KSTEPS; ++s) {
        const float* in = (s == 0) ? x : ((s & 1) ? zA : zB);
        float*       o  = (s & 1) ? zB : zA;
        const float* vi = (s & 1) ? vA : vB;   // step0: unused (firstOnes)
        float*       vo = (s & 1) ? vB : vA;
        if (s == 0) vi = vB;                   // any valid pointer
        prop64_kernel<true><<<propBlocks, 256, 0, stream>>>(
            in, x, rowptr, edata, dinv, o, vi, vo, N, s == 0 ? 1 : 0);
    }
    // zx in zB, v in vB

    // --- h2 = relu(zx@W3 + v*b3^T)@W4 + b4 ---
    fusedmlp_kernel<<<(N + 31) / 32, 256, 0, stream>>>(zB, vB, W3, b3, W4, b4, hbuf, N);

    // --- prop2: out = M*h2 ---
    for (int s = 0; s < PROP_KSTEPS; ++s) {
        const float* in = (s == 0) ? hbuf : ((s & 1) ? zA : zB);
        float*       o  = (s == PROP_KSTEPS - 1) ? out : ((s & 1) ? zB : zA);
        prop64_kernel<false><<<propBlocks, 256, 0, stream>>>(
            in, hbuf, rowptr, edata, dinv, o, nullptr, nullptr, N, 0);
    }
}